// Round 5
// baseline (756.004 us; speedup 1.0000x reference)
//
#include <hip/hip_runtime.h>

typedef float vf4 __attribute__((ext_vector_type(4)));
typedef short short8 __attribute__((ext_vector_type(8)));
typedef unsigned short ushort8 __attribute__((ext_vector_type(8)));
typedef float f32x16 __attribute__((ext_vector_type(16)));

#define LL 1024
#define DD 64
#define OO 128
#define BBATCH 4096
#define NS 511          // scan sites per sweep
#define SITE_F 8192     // elements per site tensor (64*2*64)
#define PI_2 1.57079632679489662f

// ---- async global->LDS ----
__device__ __forceinline__ void gld_lds16(const float* g, float* l) {
  __builtin_amdgcn_global_load_lds(
      (const __attribute__((address_space(1))) unsigned int*)g,
      (__attribute__((address_space(3))) unsigned int*)l, 16, 0, 0);
}

__device__ __forceinline__ void stage32k_256(float* lds, const float* g, int tid) {
#pragma unroll
  for (int q = 0; q < 8; q++) {
    const int off = (q * 256 + tid) * 4;
    gld_lds16(g + off, lds + off);
  }
}

// ---- one-shot: build bf16 fragment-major N = A - I for both sweeps ----
__global__ __launch_bounds__(256) void prep(const float* __restrict__ lsrc,
                                            const float* __restrict__ rsrc,
                                            unsigned short* __restrict__ Wl,
                                            unsigned short* __restrict__ Wr) {
  __shared__ float S[SITE_F];
  const int site = blockIdx.x;
  const int dir = blockIdx.y;
  const int tid = threadIdx.x;
  const float* src = (dir ? rsrc : lsrc) + (size_t)site * SITE_F;
  unsigned short* dst = dir ? (Wr + (size_t)(NS - 1 - site) * SITE_F)
                            : (Wl + (size_t)site * SITE_F);
#pragma unroll
  for (int m = 0; m < 8; m++)
    *(vf4*)&S[(m * 256 + tid) * 4] = *(const vf4*)&src[(m * 256 + tid) * 4];
  __syncthreads();
#pragma unroll
  for (int q = 0; q < 4; q++) {
    const int slot = q * 256 + tid;           // 0..1023 = sm*64 + lane
    const int lane = slot & 63, sm = slot >> 6;
    const int s = sm >> 1, mt = sm & 1;
    const int hi = lane >> 5, ln = lane & 31;
    const int n = 32 * mt + ln;
    ushort8 t;
#pragma unroll
    for (int j = 0; j < 8; j++) {
      const int k2 = 16 * s + 8 * hi + j;
      float v;
      if (dir == 0) {
        v = S[k2 * 64 + n] - ((n == (k2 >> 1)) ? 1.f : 0.f);
      } else {
        const int r = k2 >> 1, p = k2 & 1;
        v = S[n * 128 + p * 64 + r] - ((n == r) ? 1.f : 0.f);
      }
      const unsigned uu = __builtin_bit_cast(unsigned, v);
      t[j] = (unsigned short)((uu + 0x7FFFu + ((uu >> 16) & 1u)) >> 16);  // RNE
    }
    *(ushort8*)&dst[(size_t)slot * 8] = t;
  }
}

// ---- build B-frags for one chain ----
#define MAKE_E2(E2, U, CS, SN)                                                 \
  {                                                                            \
    _Pragma("unroll")                                                          \
    for (int s = 0; s < 8; s++) {                                              \
      int pk[4];                                                               \
      _Pragma("unroll")                                                        \
      for (int t = 0; t < 4; t++) {                                            \
        const float uv = U[s >> 2][(s & 3) * 4 + t];                           \
        const float f0 = uv * CS, f1 = uv * SN;                                \
        int p;                                                                 \
        asm("v_cvt_pk_bf16_f32 %0, %1, %2" : "=v"(p) : "v"(f0), "v"(f1));      \
        pk[t] = p;                                                             \
      }                                                                        \
      short8 e;                                                                \
      _Pragma("unroll")                                                        \
      for (int t = 0; t < 4; t++) {                                            \
        e[2 * t] = (short)(pk[t] & 0xFFFF);                                    \
        e[2 * t + 1] = (short)((unsigned)pk[t] >> 16);                         \
      }                                                                        \
      E2[s] = e;                                                               \
    }                                                                          \
  }

// ---- per-site dual-chain body ----
// FC read fresh from LDS buf (I&3); chains 0/1 share FC and staging.
#define BODY2(I, CS0, SN0, CS1, SN1, XR0, XW0, XR1, XW1, LAST)                 \
  {                                                                            \
    vf4 FC[16];                                                                \
    const float* rb = &wf[(I) & 3][0];                                         \
    _Pragma("unroll")                                                          \
    for (int q = 0; q < 16; q++)                                               \
      FC[q] = *(const vf4*)&rb[(q * 64 + lane) * 4];                           \
    const float ke0 = CS0 + SN0, ke1 = CS1 + SN1;                              \
    short8 e2a[8], e2b[8];                                                     \
    MAKE_E2(e2a, u0, CS0, SN0)                                                 \
    f32x16 a0a = {}, a0b = {}, a1a = {}, a1b = {};                             \
    _Pragma("unroll")                                                          \
    for (int s = 0; s < 4; s++) {                                              \
      a0a = __builtin_amdgcn_mfma_f32_32x32x16_bf16(                           \
          __builtin_bit_cast(short8, FC[2 * s]), e2a[s], a0a, 0, 0, 0);        \
      a1a = __builtin_amdgcn_mfma_f32_32x32x16_bf16(                           \
          __builtin_bit_cast(short8, FC[2 * s + 1]), e2a[s], a1a, 0, 0, 0);    \
    }                                                                          \
    _Pragma("unroll")                                                          \
    for (int s = 4; s < 8; s++) {                                              \
      a0b = __builtin_amdgcn_mfma_f32_32x32x16_bf16(                           \
          __builtin_bit_cast(short8, FC[2 * s]), e2a[s], a0b, 0, 0, 0);        \
      a1b = __builtin_amdgcn_mfma_f32_32x32x16_bf16(                           \
          __builtin_bit_cast(short8, FC[2 * s + 1]), e2a[s], a1b, 0, 0, 0);    \
    }                                                                          \
    MAKE_E2(e2b, u1, CS1, SN1)                                                 \
    f32x16 c0a = {}, c0b = {}, c1a = {}, c1b = {};                             \
    _Pragma("unroll")                                                          \
    for (int s = 0; s < 4; s++) {                                              \
      c0a = __builtin_amdgcn_mfma_f32_32x32x16_bf16(                           \
          __builtin_bit_cast(short8, FC[2 * s]), e2b[s], c0a, 0, 0, 0);        \
      c1a = __builtin_amdgcn_mfma_f32_32x32x16_bf16(                           \
          __builtin_bit_cast(short8, FC[2 * s + 1]), e2b[s], c1a, 0, 0, 0);    \
    }                                                                          \
    _Pragma("unroll")                                                          \
    for (int s = 4; s < 8; s++) {                                              \
      c0b = __builtin_amdgcn_mfma_f32_32x32x16_bf16(                           \
          __builtin_bit_cast(short8, FC[2 * s]), e2b[s], c0b, 0, 0, 0);        \
      c1b = __builtin_amdgcn_mfma_f32_32x32x16_bf16(                           \
          __builtin_bit_cast(short8, FC[2 * s + 1]), e2b[s], c1b, 0, 0, 0);    \
    }                                                                          \
    if (!(LAST)) {                                                             \
      const int nsite = ((I) + 3 < NS) ? ((I) + 3) : (NS - 1);                 \
      const float* Wn = W + (size_t)nsite * 4096;                              \
      float* dstb = &wf[((I) + 3) & 3][0];                                     \
      _Pragma("unroll")                                                        \
      for (int q = 0; q < 16; q++)                                             \
        gld_lds16(Wn + (q * 64 + lane) * 4, dstb + (q * 64 + lane) * 4);       \
      const int xi = dir ? (1022 - nsite) : (1 + nsite);                       \
      XW0 = xrow0[xi];                                                         \
      XW1 = xrow1[xi];                                                         \
      asm volatile("s_waitcnt vmcnt(18)" ::: "memory");                        \
      { const float ang = PI_2 * XR0; CS0 = __cosf(ang); SN0 = __sinf(ang); }  \
      { const float ang = PI_2 * XR1; CS1 = __cosf(ang); SN1 = __sinf(ang); }  \
    }                                                                          \
    _Pragma("unroll")                                                          \
    for (int r = 0; r < 16; r++) {                                             \
      u0[0][r] = ke0 * u0[0][r] + (a0a[r] + a0b[r]);                           \
      u0[1][r] = ke0 * u0[1][r] + (a1a[r] + a1b[r]);                           \
    }                                                                          \
    _Pragma("unroll")                                                          \
    for (int r = 0; r < 16; r++) {                                             \
      u1[0][r] = ke1 * u1[0][r] + (c0a[r] + c0b[r]);                           \
      u1[1][r] = ke1 * u1[1][r] + (c1a[r] + c1b[r]);                           \
    }                                                                          \
    if (((I) & 7) == 7) { /* exact pow2 rescale */                             \
      float n0 = 0.f, n1 = 0.f;                                                \
      _Pragma("unroll")                                                        \
      for (int r = 0; r < 16; r++) {                                           \
        n0 += u0[0][r] * u0[0][r] + u0[1][r] * u0[1][r];                       \
        n1 += u1[0][r] * u1[0][r] + u1[1][r] * u1[1][r];                       \
      }                                                                        \
      n0 += __shfl_xor(n0, 32);                                                \
      n1 += __shfl_xor(n1, 32);                                                \
      const int e0i = (__float_as_int(n0) >> 23) & 0xFF;                       \
      const int e1i = (__float_as_int(n1) >> 23) & 0xFF;                       \
      const float al0 = __int_as_float((127 - ((e0i - 127) >> 1)) << 23);      \
      const float al1 = __int_as_float((127 - ((e1i - 127) >> 1)) << 23);      \
      _Pragma("unroll")                                                        \
      for (int r = 0; r < 16; r++) {                                           \
        u0[0][r] *= al0; u0[1][r] *= al0;                                      \
        u1[0][r] *= al1; u1[1][r] *= al1;                                      \
      }                                                                        \
    }                                                                          \
  }

// ---- boundary init for one chain ----
#define INIT_ENV(U, XROW)                                                      \
  {                                                                            \
    const float x0 = XROW[dir ? (LL - 1) : 0];                                 \
    const float ang = PI_2 * x0;                                               \
    const float sn = __sinf(ang), cs = __cosf(ang);                            \
    _Pragma("unroll")                                                          \
    for (int mt = 0; mt < 2; mt++)                                             \
      _Pragma("unroll")                                                        \
      for (int r = 0; r < 16; r++) {                                           \
        const int n = 32 * mt + 8 * (r >> 2) + 4 * hi + (r & 3);               \
        const float w0 = dir ? right_last[n * 2] : left0[n];                   \
        const float w1 = dir ? right_last[n * 2 + 1] : left0[64 + n];          \
        U[mt][r] = cs * w0 + sn * w1;                                          \
      }                                                                        \
    float ss = 0.f;                                                            \
    _Pragma("unroll")                                                          \
    for (int mt = 0; mt < 2; mt++)                                             \
      _Pragma("unroll")                                                        \
      for (int r = 0; r < 16; r++) ss += U[mt][r] * U[mt][r];                  \
    ss += __shfl_xor(ss, 32);                                                  \
    const float a0_ = 1.f / (sqrtf(ss) + 1e-8f);                               \
    _Pragma("unroll")                                                          \
    for (int mt = 0; mt < 2; mt++)                                             \
      _Pragma("unroll")                                                        \
      for (int r = 0; r < 16; r++) U[mt][r] *= a0_;                            \
  }

// ---- sweep: 1 wave = 2 independent 32-sample chains, shared W stream ----
__global__ __launch_bounds__(64, 1) void sweep(const float* __restrict__ x,
                                               const float* __restrict__ left0,
                                               const float* __restrict__ right_last,
                                               const unsigned short* __restrict__ Wl,
                                               const unsigned short* __restrict__ Wr,
                                               float* __restrict__ envL,
                                               float* __restrict__ envR) {
  __shared__ float wf[4][4096];           // 4 x 16KB site-frag buffers
  const int bid = blockIdx.x;
  const int dir = bid >> 6;
  const int pr = bid & 63;
  const int lane = threadIdx.x;
  const int hi = lane >> 5, ln = lane & 31;
  const int b0i = (pr * 2) * 32 + ln;
  const int b1i = (pr * 2 + 1) * 32 + ln;
  const float* xrow0 = x + (size_t)b0i * LL;
  const float* xrow1 = x + (size_t)b1i * LL;

  const float* W = (const float*)(dir ? Wr : Wl);

  float u0[2][16], u1[2][16];
  INIT_ENV(u0, xrow0)
  INIT_ENV(u1, xrow1)

  // ---- prologue: x(0..2) both chains + stage sites 0..2 ----
  float xv00 = xrow0[dir ? 1022 : 1];
  float xv01 = xrow0[dir ? 1021 : 2];
  float xvB0 = xrow0[dir ? 1020 : 3];
  float xv10 = xrow1[dir ? 1022 : 1];
  float xv11 = xrow1[dir ? 1021 : 2];
  float xvB1 = xrow1[dir ? 1020 : 3];
  float xvA0, xvA1;
#pragma unroll
  for (int q = 0; q < 16; q++)
    gld_lds16(W + (q * 64 + lane) * 4, &wf[0][(q * 64 + lane) * 4]);
#pragma unroll
  for (int q = 0; q < 16; q++)
    gld_lds16(W + (size_t)1 * 4096 + (q * 64 + lane) * 4, &wf[1][(q * 64 + lane) * 4]);
#pragma unroll
  for (int q = 0; q < 16; q++)
    gld_lds16(W + (size_t)2 * 4096 + (q * 64 + lane) * 4, &wf[2][(q * 64 + lane) * 4]);
  asm volatile("s_waitcnt vmcnt(32)" ::: "memory");

  float csE0, snE0, csO0, snO0, csE1, snE1, csO1, snO1;
  { const float ang = PI_2 * xv00; csE0 = __cosf(ang); snE0 = __sinf(ang); }
  { const float ang = PI_2 * xv01; csO0 = __cosf(ang); snO0 = __sinf(ang); }
  { const float ang = PI_2 * xv10; csE1 = __cosf(ang); snE1 = __sinf(ang); }
  { const float ang = PI_2 * xv11; csO1 = __cosf(ang); snO1 = __sinf(ang); }

  // ---- main loop: sites 0..509 unrolled x2, tail site 510 ----
  for (int i = 0; i < NS - 1; i += 2) {
    BODY2(i, csE0, snE0, csE1, snE1, xvB0, xvA0, xvB1, xvA1, 0)
    BODY2(i + 1, csO0, snO0, csO1, snO1, xvA0, xvB0, xvA1, xvB1, 0)
  }
  BODY2(NS - 1, csE0, snE0, csE1, snE1, xvB0, xvA0, xvB1, xvA1, 1)

  // ---- final exact normalize + store, both chains ----
  float* eoB = dir ? envR : envL;
  {
    float nss = 0.f;
#pragma unroll
    for (int mt = 0; mt < 2; mt++)
#pragma unroll
      for (int r = 0; r < 16; r++) nss += u0[mt][r] * u0[mt][r];
    nss += __shfl_xor(nss, 32);
    const float alpha = 1.f / (sqrtf(nss) + 1e-8f);
    float* eo = eoB + (size_t)b0i * 64;
#pragma unroll
    for (int mt = 0; mt < 2; mt++)
#pragma unroll
      for (int g = 0; g < 4; g++) {
        vf4 v;
#pragma unroll
        for (int q = 0; q < 4; q++) v[q] = u0[mt][g * 4 + q] * alpha;
        *(vf4*)&eo[32 * mt + 8 * g + 4 * hi] = v;
      }
  }
  {
    float nss = 0.f;
#pragma unroll
    for (int mt = 0; mt < 2; mt++)
#pragma unroll
      for (int r = 0; r < 16; r++) nss += u1[mt][r] * u1[mt][r];
    nss += __shfl_xor(nss, 32);
    const float alpha = 1.f / (sqrtf(nss) + 1e-8f);
    float* eo = eoB + (size_t)b1i * 64;
#pragma unroll
    for (int mt = 0; mt < 2; mt++)
#pragma unroll
      for (int g = 0; g < 4; g++) {
        vf4 v;
#pragma unroll
        for (int q = 0; q < 4; q++) v[q] = u1[mt][g * 4 + q] * alpha;
        *(vf4*)&eo[32 * mt + 8 * g + 4 * hi] = v;
      }
  }
  asm volatile("s_waitcnt vmcnt(0)" ::: "memory");  // drain tail prefetches
}

// ---- center contraction (fp32) ----
__global__ __launch_bounds__(256) void centerk(const float* __restrict__ envL,
                                               const float* __restrict__ envR,
                                               const float* __restrict__ center,
                                               float* __restrict__ Pp) {
  __shared__ float Cs[2][SITE_F];
  __shared__ float LT[64 * 36];
  __shared__ float RT[64 * 36];
  const int bbase = blockIdx.x * 32;
  const int half = blockIdx.y;
  const int tid = threadIdx.x;
  const int och = tid & 31, bch = tid >> 5;
  const int o0 = och * 4, b0 = bch * 4;
#pragma unroll
  for (int m = 0; m < 8; m++) {
    const int idx = m * 256 + tid;
    const int b = idx >> 6, l = idx & 63;
    LT[l * 36 + b] = envL[(bbase + b) * 64 + l];
    RT[l * 36 + b] = envR[(bbase + b) * 64 + l];
  }
  stage32k_256(Cs[0], center + (half * 32) * SITE_F, tid);
  float acc[4][4] = {};
  for (int lh = 0; lh < 32; lh++) {
    __syncthreads();
    const int buf = lh & 1;
    if (lh + 1 < 32) stage32k_256(Cs[buf ^ 1], center + (half * 32 + lh + 1) * SITE_F, tid);
    const vf4 lv = *(const vf4*)&LT[(half * 32 + lh) * 36 + b0];
    const float* C = Cs[buf];
#pragma unroll
    for (int r = 0; r < 64; r++) {
      const vf4 rv = *(const vf4*)&RT[r * 36 + b0];
      const vf4 cv = *(const vf4*)&C[r * 128 + o0];
#pragma unroll
      for (int i2 = 0; i2 < 4; i2++) {
        const float w = lv[i2] * rv[i2];
        acc[i2][0] += w * cv[0];
        acc[i2][1] += w * cv[1];
        acc[i2][2] += w * cv[2];
        acc[i2][3] += w * cv[3];
      }
    }
  }
#pragma unroll
  for (int i2 = 0; i2 < 4; i2++) {
    vf4 v; v[0] = acc[i2][0]; v[1] = acc[i2][1]; v[2] = acc[i2][2]; v[3] = acc[i2][3];
    *(vf4*)&Pp[(size_t)half * BBATCH * 128 + (size_t)(bbase + b0 + i2) * 128 + o0] = v;
  }
}

// ---- combine halves + row-normalize ----
__global__ __launch_bounds__(256) void combinek(const float* __restrict__ P,
                                                float* __restrict__ out) {
  const float* P0 = P;
  const float* P1 = P + (size_t)BBATCH * 128;
  const int row = blockIdx.x * 8 + (threadIdx.x >> 5);
  const int o0 = (threadIdx.x & 31) * 4;
  vf4 v = *(const vf4*)&P0[(size_t)row * 128 + o0];
  const vf4 v1 = *(const vf4*)&P1[(size_t)row * 128 + o0];
  v += v1;
  float ss = v[0] * v[0] + v[1] * v[1] + v[2] * v[2] + v[3] * v[3];
#pragma unroll
  for (int m = 1; m < 32; m <<= 1) ss += __shfl_xor(ss, m);
  const float inv = 1.f / fmaxf(sqrtf(ss), 1e-12f);
  v *= inv;
  *(vf4*)&out[(size_t)row * 128 + o0] = v;
}

extern "C" void kernel_launch(void* const* d_in, const int* in_sizes, int n_in,
                              void* d_out, int out_size, void* d_ws, size_t ws_size,
                              hipStream_t stream) {
  const float* x = (const float*)d_in[0];
  const float* left0 = (const float*)d_in[1];
  const float* left_rest = (const float*)d_in[2];
  const float* center = (const float*)d_in[3];
  const float* right_rest = (const float*)d_in[4];
  const float* right_last = (const float*)d_in[5];
  float* out = (float*)d_out;

  char* wsb = (char*)d_ws;
  unsigned short* Wl = (unsigned short*)wsb;                       // 8.37 MB
  unsigned short* Wr = Wl + (size_t)NS * SITE_F;                   // 8.37 MB
  float* envL = (float*)(Wr + (size_t)NS * SITE_F);                // 1 MB
  float* envR = envL + (size_t)BBATCH * 64;                        // 1 MB
  float* Pp = envR + (size_t)BBATCH * 64;                          // 4.2 MB

  hipLaunchKernelGGL(prep, dim3(NS, 2), dim3(256), 0, stream,
                     left_rest, right_rest, Wl, Wr);
  hipLaunchKernelGGL(sweep, dim3(128), dim3(64), 0, stream,
                     x, left0, right_last, Wl, Wr, envL, envR);
  hipLaunchKernelGGL(centerk, dim3(BBATCH / 32, 2), dim3(256), 0, stream,
                     envL, envR, center, Pp);
  hipLaunchKernelGGL(combinek, dim3(BBATCH / 8), dim3(256), 0, stream, Pp, out);
}

// Round 6
// 569.732 us; speedup vs baseline: 1.3269x; 1.3269x over previous
//
#include <hip/hip_runtime.h>

typedef float vf4 __attribute__((ext_vector_type(4)));
typedef short short8 __attribute__((ext_vector_type(8)));
typedef unsigned short ushort8 __attribute__((ext_vector_type(8)));
typedef float f32x16 __attribute__((ext_vector_type(16)));

#define LL 1024
#define DD 64
#define OO 128
#define BBATCH 4096
#define NS 511          // scan sites per sweep
#define SITE_F 8192     // elements per site tensor (64*2*64)
#define PI_2 1.57079632679489662f

// ---- async global->LDS ----
__device__ __forceinline__ void gld_lds16(const float* g, float* l) {
  __builtin_amdgcn_global_load_lds(
      (const __attribute__((address_space(1))) unsigned int*)g,
      (__attribute__((address_space(3))) unsigned int*)l, 16, 0, 0);
}
__device__ __forceinline__ void gld_lds4(const float* g, float* l) {
  __builtin_amdgcn_global_load_lds(
      (const __attribute__((address_space(1))) unsigned int*)g,
      (__attribute__((address_space(3))) unsigned int*)l, 4, 0, 0);
}

__device__ __forceinline__ void stage32k_256(float* lds, const float* g, int tid) {
#pragma unroll
  for (int q = 0; q < 8; q++) {
    const int off = (q * 256 + tid) * 4;
    gld_lds16(g + off, lds + off);
  }
}

// ---- one-shot: build bf16 fragment-major N = A - I for both sweeps ----
__global__ __launch_bounds__(256) void prep(const float* __restrict__ lsrc,
                                            const float* __restrict__ rsrc,
                                            unsigned short* __restrict__ Wl,
                                            unsigned short* __restrict__ Wr) {
  __shared__ float S[SITE_F];
  const int site = blockIdx.x;
  const int dir = blockIdx.y;
  const int tid = threadIdx.x;
  const float* src = (dir ? rsrc : lsrc) + (size_t)site * SITE_F;
  unsigned short* dst = dir ? (Wr + (size_t)(NS - 1 - site) * SITE_F)
                            : (Wl + (size_t)site * SITE_F);
#pragma unroll
  for (int m = 0; m < 8; m++)
    *(vf4*)&S[(m * 256 + tid) * 4] = *(const vf4*)&src[(m * 256 + tid) * 4];
  __syncthreads();
#pragma unroll
  for (int q = 0; q < 4; q++) {
    const int slot = q * 256 + tid;           // 0..1023 = sm*64 + lane
    const int lane = slot & 63, sm = slot >> 6;
    const int s = sm >> 1, mt = sm & 1;
    const int hi = lane >> 5, ln = lane & 31;
    const int n = 32 * mt + ln;
    ushort8 t;
#pragma unroll
    for (int j = 0; j < 8; j++) {
      const int k2 = 16 * s + 8 * hi + j;
      float v;
      if (dir == 0) {
        v = S[k2 * 64 + n] - ((n == (k2 >> 1)) ? 1.f : 0.f);
      } else {
        const int r = k2 >> 1, p = k2 & 1;
        v = S[n * 128 + p * 64 + r] - ((n == r) ? 1.f : 0.f);
      }
      const unsigned uu = __builtin_bit_cast(unsigned, v);
      t[j] = (unsigned short)((uu + 0x7FFFu + ((uu >> 16) & 1u)) >> 16);  // RNE
    }
    *(ushort8*)&dst[(size_t)slot * 8] = t;
  }
}

// ---- stage x chunk c (128 sites x 32 samples, [t][s] layout) ----
// linear elem e = q*64 + lane ; t_loc = e>>5 = 2q+hi ; s = e&31 = ln
#define STAGE_X(C, BUFP)                                                       \
  {                                                                            \
    const int t0x = dir ? (1022 - 128 * (C) - hi) : (1 + 128 * (C) + hi);      \
    const float* px = xrowB + t0x;                                             \
    const int stp = dir ? -2 : 2;                                              \
    float* xdst = &xb[BUFP][0][0];                                             \
    _Pragma("unroll")                                                          \
    for (int q = 0; q < 64; q++)                                               \
      gld_lds4(px + q * stp, xdst + q * 64 + lane);                            \
  }

// ---- per-site body, macro for static reg naming ----
// FC: frag regs for site I; FN: filled with site I+1 frags from LDS
// CSc/SNc: cos/sin for site I; CSn/SNn: written with site I+1's (from LDS x)
#define BODY(I, FC, FN, CSc, SNc, CSn, SNn, LAST)                              \
  {                                                                            \
    const float keff = CSc + SNc;                                              \
    short8 e2[8];                                                              \
    _Pragma("unroll")                                                          \
    for (int s = 0; s < 8; s++) {                                              \
      int pk[4];                                                               \
      _Pragma("unroll")                                                        \
      for (int t = 0; t < 4; t++) {                                            \
        const float uv = u[s >> 2][(s & 3) * 4 + t];                           \
        const float f0 = uv * CSc, f1 = uv * SNc;                              \
        int p;                                                                 \
        asm("v_cvt_pk_bf16_f32 %0, %1, %2" : "=v"(p) : "v"(f0), "v"(f1));      \
        pk[t] = p;                                                             \
      }                                                                        \
      short8 e;                                                                \
      _Pragma("unroll")                                                        \
      for (int t = 0; t < 4; t++) {                                            \
        e[2 * t] = (short)(pk[t] & 0xFFFF);                                    \
        e[2 * t + 1] = (short)((unsigned)pk[t] >> 16);                         \
      }                                                                        \
      e2[s] = e;                                                               \
    }                                                                          \
    f32x16 a0a = {}, a0b = {}, a1a = {}, a1b = {};                             \
    _Pragma("unroll")                                                          \
    for (int s = 0; s < 4; s++) {                                              \
      a0a = __builtin_amdgcn_mfma_f32_32x32x16_bf16(                           \
          __builtin_bit_cast(short8, FC[2 * s]), e2[s], a0a, 0, 0, 0);         \
      a1a = __builtin_amdgcn_mfma_f32_32x32x16_bf16(                           \
          __builtin_bit_cast(short8, FC[2 * s + 1]), e2[s], a1a, 0, 0, 0);     \
    }                                                                          \
    _Pragma("unroll")                                                          \
    for (int s = 4; s < 8; s++) {                                              \
      a0b = __builtin_amdgcn_mfma_f32_32x32x16_bf16(                           \
          __builtin_bit_cast(short8, FC[2 * s]), e2[s], a0b, 0, 0, 0);         \
      a1b = __builtin_amdgcn_mfma_f32_32x32x16_bf16(                           \
          __builtin_bit_cast(short8, FC[2 * s + 1]), e2[s], a1b, 0, 0, 0);     \
    }                                                                          \
    if (!(LAST)) {                                                             \
      const int nsite = ((I) + 3 < NS) ? ((I) + 3) : (NS - 1);                 \
      const float* Wn = W + (size_t)nsite * 4096;                              \
      float* dstb = &wf[((I) + 3) & 3][0];                                     \
      _Pragma("unroll")                                                        \
      for (int q = 0; q < 16; q++)                                             \
        gld_lds16(Wn + (q * 64 + lane) * 4, dstb + (q * 64 + lane) * 4);       \
      asm volatile("s_waitcnt vmcnt(32)" ::: "memory");                        \
      const float* rb = &wf[((I) + 1) & 3][0];                                 \
      _Pragma("unroll")                                                        \
      for (int q = 0; q < 16; q++)                                             \
        FN[q] = *(const vf4*)&rb[(q * 64 + lane) * 4];                         \
      const float xnext = xb[(((I) + 1) >> 7) & 1][((I) + 1) & 127][ln];       \
      const float ang = PI_2 * xnext;                                          \
      CSn = __cosf(ang);                                                       \
      SNn = __sinf(ang);                                                       \
    }                                                                          \
    _Pragma("unroll")                                                          \
    for (int r = 0; r < 16; r++) {                                             \
      u[0][r] = keff * u[0][r] + (a0a[r] + a0b[r]);                            \
      u[1][r] = keff * u[1][r] + (a1a[r] + a1b[r]);                            \
    }                                                                          \
    if (((I) & 7) == 7) { /* exact pow2 rescale, keeps fp32 in range */        \
      float nss = 0.f;                                                         \
      _Pragma("unroll")                                                        \
      for (int r = 0; r < 16; r++)                                             \
        nss += u[0][r] * u[0][r] + u[1][r] * u[1][r];                          \
      nss += __shfl_xor(nss, 32);                                              \
      const int eb = (__float_as_int(nss) >> 23) & 0xFF;                       \
      const float alpha = __int_as_float((127 - ((eb - 127) >> 1)) << 23);     \
      _Pragma("unroll")                                                        \
      for (int r = 0; r < 16; r++) { u[0][r] *= alpha; u[1][r] *= alpha; }     \
    }                                                                          \
  }

// ---- sweep: 1 wave = 32 batch chains; no VGPR global loads in loop ----
__global__ __launch_bounds__(64, 1) void sweep(const float* __restrict__ x,
                                               const float* __restrict__ left0,
                                               const float* __restrict__ right_last,
                                               const unsigned short* __restrict__ Wl,
                                               const unsigned short* __restrict__ Wr,
                                               float* __restrict__ envL,
                                               float* __restrict__ envR) {
  __shared__ float wf[4][4096];           // 4 x 16KB site-frag buffers
  __shared__ float xb[2][128][32];        // 2 x 16KB x chunks, [t][s]
  const int bid = blockIdx.x;
  const int dir = bid >> 7;
  const int pr = bid & 127;
  const int lane = threadIdx.x;
  const int hi = lane >> 5, ln = lane & 31;
  const int b = pr * 32 + ln;
  const float* xrowB = x + (size_t)b * LL;

  const float* W = (const float*)(dir ? Wr : Wl);

  // init env from boundary tensor (fp32, exact normalize; prologue-only
  // global scalar loads)
  float u[2][16];
  {
    const float x0 = xrowB[dir ? (LL - 1) : 0];
    const float ang = PI_2 * x0;
    const float sn = __sinf(ang), cs = __cosf(ang);
#pragma unroll
    for (int mt = 0; mt < 2; mt++)
#pragma unroll
      for (int r = 0; r < 16; r++) {
        const int n = 32 * mt + 8 * (r >> 2) + 4 * hi + (r & 3);
        const float w0 = dir ? right_last[n * 2] : left0[n];
        const float w1 = dir ? right_last[n * 2 + 1] : left0[64 + n];
        u[mt][r] = cs * w0 + sn * w1;
      }
    float ss = 0.f;
#pragma unroll
    for (int mt = 0; mt < 2; mt++)
#pragma unroll
      for (int r = 0; r < 16; r++) ss += u[mt][r] * u[mt][r];
    ss += __shfl_xor(ss, 32);
    const float a0 = 1.f / (sqrtf(ss) + 1e-8f);
#pragma unroll
    for (int mt = 0; mt < 2; mt++)
#pragma unroll
      for (int r = 0; r < 16; r++) u[mt][r] *= a0;
  }

  // ---- prologue: stage W sites 0..2 + x chunk 0; then frag(0), cs/sn(0) ----
#pragma unroll
  for (int q = 0; q < 16; q++)
    gld_lds16(W + (q * 64 + lane) * 4, &wf[0][(q * 64 + lane) * 4]);
#pragma unroll
  for (int q = 0; q < 16; q++)
    gld_lds16(W + (size_t)1 * 4096 + (q * 64 + lane) * 4, &wf[1][(q * 64 + lane) * 4]);
#pragma unroll
  for (int q = 0; q < 16; q++)
    gld_lds16(W + (size_t)2 * 4096 + (q * 64 + lane) * 4, &wf[2][(q * 64 + lane) * 4]);
  STAGE_X(0, 0)
  asm volatile("s_waitcnt vmcnt(0)" ::: "memory");

  vf4 fA[16], fB[16];
#pragma unroll
  for (int q = 0; q < 16; q++)
    fA[q] = *(const vf4*)&wf[0][(q * 64 + lane) * 4];

  float csE, snE, csO, snO;
  {
    const float ang = PI_2 * xb[0][0][ln];
    csE = __cosf(ang);
    snE = __sinf(ang);
  }

  // ---- main loop: sites 0..509 unrolled x2, tail site 510 ----
  for (int i = 0; i < NS - 1; i += 2) {
    if ((i & 127) == 0 && (i >> 7) + 1 <= 3) {
      const int c = (i >> 7) + 1;
      STAGE_X(c, c & 1)
    }
    BODY(i, fA, fB, csE, snE, csO, snO, 0)
    BODY(i + 1, fB, fA, csO, snO, csE, snE, 0)
  }
  BODY(NS - 1, fA, fB, csE, snE, csO, snO, 1)

  // final exact normalize + store
  float nss = 0.f;
#pragma unroll
  for (int mt = 0; mt < 2; mt++)
#pragma unroll
    for (int r = 0; r < 16; r++) nss += u[mt][r] * u[mt][r];
  nss += __shfl_xor(nss, 32);
  const float alpha = 1.f / (sqrtf(nss) + 1e-8f);

  float* eo = (dir ? envR : envL) + (size_t)b * 64;
#pragma unroll
  for (int mt = 0; mt < 2; mt++)
#pragma unroll
    for (int g = 0; g < 4; g++) {
      vf4 v;
#pragma unroll
      for (int q = 0; q < 4; q++) v[q] = u[mt][g * 4 + q] * alpha;
      *(vf4*)&eo[32 * mt + 8 * g + 4 * hi] = v;
    }
  asm volatile("s_waitcnt vmcnt(0)" ::: "memory");  // drain tail prefetches
}

// ---- center contraction (fp32) ----
__global__ __launch_bounds__(256) void centerk(const float* __restrict__ envL,
                                               const float* __restrict__ envR,
                                               const float* __restrict__ center,
                                               float* __restrict__ Pp) {
  __shared__ float Cs[2][SITE_F];
  __shared__ float LT[64 * 36];
  __shared__ float RT[64 * 36];
  const int bbase = blockIdx.x * 32;
  const int half = blockIdx.y;
  const int tid = threadIdx.x;
  const int och = tid & 31, bch = tid >> 5;
  const int o0 = och * 4, b0 = bch * 4;
#pragma unroll
  for (int m = 0; m < 8; m++) {
    const int idx = m * 256 + tid;
    const int b = idx >> 6, l = idx & 63;
    LT[l * 36 + b] = envL[(bbase + b) * 64 + l];
    RT[l * 36 + b] = envR[(bbase + b) * 64 + l];
  }
  stage32k_256(Cs[0], center + (half * 32) * SITE_F, tid);
  float acc[4][4] = {};
  for (int lh = 0; lh < 32; lh++) {
    __syncthreads();
    const int buf = lh & 1;
    if (lh + 1 < 32) stage32k_256(Cs[buf ^ 1], center + (half * 32 + lh + 1) * SITE_F, tid);
    const vf4 lv = *(const vf4*)&LT[(half * 32 + lh) * 36 + b0];
    const float* C = Cs[buf];
#pragma unroll
    for (int r = 0; r < 64; r++) {
      const vf4 rv = *(const vf4*)&RT[r * 36 + b0];
      const vf4 cv = *(const vf4*)&C[r * 128 + o0];
#pragma unroll
      for (int i2 = 0; i2 < 4; i2++) {
        const float w = lv[i2] * rv[i2];
        acc[i2][0] += w * cv[0];
        acc[i2][1] += w * cv[1];
        acc[i2][2] += w * cv[2];
        acc[i2][3] += w * cv[3];
      }
    }
  }
#pragma unroll
  for (int i2 = 0; i2 < 4; i2++) {
    vf4 v; v[0] = acc[i2][0]; v[1] = acc[i2][1]; v[2] = acc[i2][2]; v[3] = acc[i2][3];
    *(vf4*)&Pp[(size_t)half * BBATCH * 128 + (size_t)(bbase + b0 + i2) * 128 + o0] = v;
  }
}

// ---- combine halves + row-normalize ----
__global__ __launch_bounds__(256) void combinek(const float* __restrict__ P,
                                                float* __restrict__ out) {
  const float* P0 = P;
  const float* P1 = P + (size_t)BBATCH * 128;
  const int row = blockIdx.x * 8 + (threadIdx.x >> 5);
  const int o0 = (threadIdx.x & 31) * 4;
  vf4 v = *(const vf4*)&P0[(size_t)row * 128 + o0];
  const vf4 v1 = *(const vf4*)&P1[(size_t)row * 128 + o0];
  v += v1;
  float ss = v[0] * v[0] + v[1] * v[1] + v[2] * v[2] + v[3] * v[3];
#pragma unroll
  for (int m = 1; m < 32; m <<= 1) ss += __shfl_xor(ss, m);
  const float inv = 1.f / fmaxf(sqrtf(ss), 1e-12f);
  v *= inv;
  *(vf4*)&out[(size_t)row * 128 + o0] = v;
}

extern "C" void kernel_launch(void* const* d_in, const int* in_sizes, int n_in,
                              void* d_out, int out_size, void* d_ws, size_t ws_size,
                              hipStream_t stream) {
  const float* x = (const float*)d_in[0];
  const float* left0 = (const float*)d_in[1];
  const float* left_rest = (const float*)d_in[2];
  const float* center = (const float*)d_in[3];
  const float* right_rest = (const float*)d_in[4];
  const float* right_last = (const float*)d_in[5];
  float* out = (float*)d_out;

  char* wsb = (char*)d_ws;
  unsigned short* Wl = (unsigned short*)wsb;                       // 8.37 MB
  unsigned short* Wr = Wl + (size_t)NS * SITE_F;                   // 8.37 MB
  float* envL = (float*)(Wr + (size_t)NS * SITE_F);                // 1 MB
  float* envR = envL + (size_t)BBATCH * 64;                        // 1 MB
  float* Pp = envR + (size_t)BBATCH * 64;                          // 4.2 MB

  hipLaunchKernelGGL(prep, dim3(NS, 2), dim3(256), 0, stream,
                     left_rest, right_rest, Wl, Wr);
  hipLaunchKernelGGL(sweep, dim3(256), dim3(64), 0, stream,
                     x, left0, right_last, Wl, Wr, envL, envR);
  hipLaunchKernelGGL(centerk, dim3(BBATCH / 32, 2), dim3(256), 0, stream,
                     envL, envR, center, Pp);
  hipLaunchKernelGGL(combinek, dim3(BBATCH / 8), dim3(256), 0, stream, Pp, out);
}

// Round 7
// 431.921 us; speedup vs baseline: 1.7503x; 1.3191x over previous
//
#include <hip/hip_runtime.h>

typedef float vf4 __attribute__((ext_vector_type(4)));
typedef short short8 __attribute__((ext_vector_type(8)));
typedef unsigned short ushort8 __attribute__((ext_vector_type(8)));

#define LL 1024
#define DD 64
#define OO 128
#define BBATCH 4096
#define NS 511          // scan sites per sweep
#define SITE_F 8192     // elements per site tensor (64*2*64)
#define PI_2 1.57079632679489662f

// ---- async global->LDS (used by centerk only) ----
__device__ __forceinline__ void gld_lds16(const float* g, float* l) {
  __builtin_amdgcn_global_load_lds(
      (const __attribute__((address_space(1))) unsigned int*)g,
      (__attribute__((address_space(3))) unsigned int*)l, 16, 0, 0);
}

__device__ __forceinline__ void stage32k_256(float* lds, const float* g, int tid) {
#pragma unroll
  for (int q = 0; q < 8; q++) {
    const int off = (q * 256 + tid) * 4;
    gld_lds16(g + off, lds + off);
  }
}

// ---- one-shot: build bf16 16x16x32-frag-major N = A - I for both sweeps ----
// layout: W[site][f][lane][j] bf16, f = mt*4+s (mt=M-tile 0..3, s=K-step 0..3)
// A elem: m = 16*mt + (lane&15); k = 32*s + 8*(lane>>4) + j  (k2 = 2*env_in + p)
// right buffer is site-reversed so the sweep always walks ascending.
__global__ __launch_bounds__(256) void prep(const float* __restrict__ lsrc,
                                            const float* __restrict__ rsrc,
                                            unsigned short* __restrict__ Wl,
                                            unsigned short* __restrict__ Wr) {
  __shared__ float S[SITE_F];
  const int site = blockIdx.x;
  const int dir = blockIdx.y;
  const int tid = threadIdx.x;
  const float* src = (dir ? rsrc : lsrc) + (size_t)site * SITE_F;
  unsigned short* dst = dir ? (Wr + (size_t)(NS - 1 - site) * SITE_F)
                            : (Wl + (size_t)site * SITE_F);
#pragma unroll
  for (int m = 0; m < 8; m++)
    *(vf4*)&S[(m * 256 + tid) * 4] = *(const vf4*)&src[(m * 256 + tid) * 4];
  __syncthreads();
#pragma unroll
  for (int q = 0; q < 4; q++) {
    const int slot = q * 256 + tid;           // 0..1023 = f*64 + lane
    const int lane = slot & 63, f = slot >> 6;
    const int mt = f >> 2, s = f & 3;
    const int g = lane >> 4, c = lane & 15;
    const int m = 16 * mt + c;
    ushort8 t;
#pragma unroll
    for (int j = 0; j < 8; j++) {
      const int k = 32 * s + 8 * g + j;
      float v;
      if (dir == 0) {
        // left: A[m=r][k=(l,p)] = lsrc[l][p][m] - delta_{l,m}
        const int l = k >> 1, p = k & 1;
        v = S[l * 128 + p * 64 + m] - ((m == l) ? 1.f : 0.f);
      } else {
        // right: A[m=l][k=(r,p)] = rsrc[m][p][r] - delta_{m,r}
        const int r = k >> 1, p = k & 1;
        v = S[m * 128 + p * 64 + r] - ((m == r) ? 1.f : 0.f);
      }
      const unsigned uu = __builtin_bit_cast(unsigned, v);
      t[j] = (unsigned short)((uu + 0x7FFFu + ((uu >> 16) & 1u)) >> 16);  // RNE
    }
    *(ushort8*)&dst[(size_t)slot * 8] = t;
  }
}

// ---- per-site body; all loads are plain global->VGPR, compiler-scheduled ----
// FC: frags for site I; FN: filled with site I+1 frags (global vf4 loads)
// CSc/SNc: cos/sin for site I; CSn/SNn receive site I+1's (from XR = x(I+1))
// XW receives x(I+2).
#define BODY(I, FC, FN, CSc, SNc, CSn, SNn, XR, XW, LAST)                      \
  {                                                                            \
    if (!(LAST)) {                                                             \
      const unsigned short* Wn = W + (size_t)((I) + 1) * SITE_F;               \
      _Pragma("unroll")                                                        \
      for (int q = 0; q < 16; q++)                                             \
        FN[q] = *(const vf4*)&Wn[(q * 64 + lane) * 8];                         \
      XW = xrow[dir ? (1020 - (I)) : (3 + (I))];                               \
    }                                                                          \
    short8 e2[4];                                                              \
    _Pragma("unroll")                                                          \
    for (int s = 0; s < 4; s++) {                                              \
      int pk[4];                                                               \
      _Pragma("unroll")                                                        \
      for (int t = 0; t < 4; t++) {                                            \
        const float f0 = u[s][t] * CSc, f1 = u[s][t] * SNc;                    \
        int p;                                                                 \
        asm("v_cvt_pk_bf16_f32 %0, %1, %2" : "=v"(p) : "v"(f0), "v"(f1));      \
        pk[t] = p;                                                             \
      }                                                                        \
      short8 e;                                                                \
      _Pragma("unroll")                                                        \
      for (int t = 0; t < 4; t++) {                                            \
        e[2 * t] = (short)(pk[t] & 0xFFFF);                                    \
        e[2 * t + 1] = (short)((unsigned)pk[t] >> 16);                         \
      }                                                                        \
      e2[s] = e;                                                               \
    }                                                                          \
    const float keff = CSc + SNc;                                              \
    vf4 ac0[4], ac1[4];                                                        \
    _Pragma("unroll")                                                          \
    for (int mt = 0; mt < 4; mt++) {                                           \
      vf4 z;                                                                   \
      z[0] = keff * u[mt][0]; z[1] = keff * u[mt][1];                          \
      z[2] = keff * u[mt][2]; z[3] = keff * u[mt][3];                          \
      ac0[mt] = z;                                                             \
      ac1[mt] = (vf4){0.f, 0.f, 0.f, 0.f};                                     \
    }                                                                          \
    _Pragma("unroll")                                                          \
    for (int mt = 0; mt < 4; mt++) {                                           \
      ac0[mt] = __builtin_amdgcn_mfma_f32_16x16x32_bf16(                       \
          __builtin_bit_cast(short8, FC[mt * 4 + 0]), e2[0], ac0[mt], 0, 0, 0);\
      ac0[mt] = __builtin_amdgcn_mfma_f32_16x16x32_bf16(                       \
          __builtin_bit_cast(short8, FC[mt * 4 + 1]), e2[1], ac0[mt], 0, 0, 0);\
      ac1[mt] = __builtin_amdgcn_mfma_f32_16x16x32_bf16(                       \
          __builtin_bit_cast(short8, FC[mt * 4 + 2]), e2[2], ac1[mt], 0, 0, 0);\
      ac1[mt] = __builtin_amdgcn_mfma_f32_16x16x32_bf16(                       \
          __builtin_bit_cast(short8, FC[mt * 4 + 3]), e2[3], ac1[mt], 0, 0, 0);\
    }                                                                          \
    if (!(LAST)) {                                                             \
      const float ang = PI_2 * XR;                                             \
      CSn = __cosf(ang);                                                       \
      SNn = __sinf(ang);                                                       \
    }                                                                          \
    _Pragma("unroll")                                                          \
    for (int mt = 0; mt < 4; mt++) {                                           \
      u[mt][0] = ac0[mt][0] + ac1[mt][0];                                      \
      u[mt][1] = ac0[mt][1] + ac1[mt][1];                                      \
      u[mt][2] = ac0[mt][2] + ac1[mt][2];                                      \
      u[mt][3] = ac0[mt][3] + ac1[mt][3];                                      \
    }                                                                          \
    if (((I) & 7) == 7) { /* exact pow2 rescale, keeps fp32 in range */        \
      float nss = 0.f;                                                         \
      _Pragma("unroll")                                                        \
      for (int mt = 0; mt < 4; mt++)                                           \
        _Pragma("unroll")                                                      \
        for (int r = 0; r < 4; r++) nss += u[mt][r] * u[mt][r];                \
      nss += __shfl_xor(nss, 16);                                              \
      nss += __shfl_xor(nss, 32);                                              \
      const int eb = (__float_as_int(nss) >> 23) & 0xFF;                       \
      const float alpha = __int_as_float((127 - ((eb - 127) >> 1)) << 23);     \
      _Pragma("unroll")                                                        \
      for (int mt = 0; mt < 4; mt++)                                           \
        _Pragma("unroll")                                                      \
        for (int r = 0; r < 4; r++) u[mt][r] *= alpha;                         \
    }                                                                          \
  }

// ---- sweep: 1 wave = 16 batch chains, no LDS, register double-buffer ----
// 512 blocks -> 2 blocks/CU -> 2 SIMDs busy per CU.
__global__ __launch_bounds__(64, 1) void sweep(const float* __restrict__ x,
                                               const float* __restrict__ left0,
                                               const float* __restrict__ right_last,
                                               const unsigned short* __restrict__ Wl,
                                               const unsigned short* __restrict__ Wr,
                                               float* __restrict__ envL,
                                               float* __restrict__ envR) {
  const int bid = blockIdx.x;
  const int dir = bid >> 8;
  const int pr = bid & 255;
  const int lane = threadIdx.x;
  const int g = lane >> 4, c = lane & 15;
  const int b = pr * 16 + c;
  const float* xrow = x + (size_t)b * LL;

  const unsigned short* W = dir ? Wr : Wl;

  // init env from boundary tensor (fp32, exact normalize)
  float u[4][4];
  {
    const float x0 = xrow[dir ? (LL - 1) : 0];
    const float ang = PI_2 * x0;
    const float sn = __sinf(ang), cs = __cosf(ang);
#pragma unroll
    for (int mt = 0; mt < 4; mt++)
#pragma unroll
      for (int r = 0; r < 4; r++) {
        const int n = 16 * mt + 4 * g + r;
        const float w0 = dir ? right_last[n * 2] : left0[n];
        const float w1 = dir ? right_last[n * 2 + 1] : left0[64 + n];
        u[mt][r] = cs * w0 + sn * w1;
      }
    float ss = 0.f;
#pragma unroll
    for (int mt = 0; mt < 4; mt++)
#pragma unroll
      for (int r = 0; r < 4; r++) ss += u[mt][r] * u[mt][r];
    ss += __shfl_xor(ss, 16);
    ss += __shfl_xor(ss, 32);
    const float a0 = 1.f / (sqrtf(ss) + 1e-8f);
#pragma unroll
    for (int mt = 0; mt < 4; mt++)
#pragma unroll
      for (int r = 0; r < 4; r++) u[mt][r] *= a0;
  }

  // ---- prologue: frags(site0) + x ring ----
  vf4 fA[16], fB[16];
#pragma unroll
  for (int q = 0; q < 16; q++)
    fA[q] = *(const vf4*)&W[(q * 64 + lane) * 8];

  float csE, snE, csO, snO;
  {
    const float ang = PI_2 * xrow[dir ? 1022 : 1];   // x for site 0
    csE = __cosf(ang);
    snE = __sinf(ang);
  }
  float xvA = xrow[dir ? 1021 : 2];   // x for site 1
  float xvB;

  // ---- main loop: sites 0..509 unrolled x2, tail site 510 ----
  for (int i = 0; i < NS - 1; i += 2) {
    BODY(i, fA, fB, csE, snE, csO, snO, xvA, xvB, 0)
    BODY(i + 1, fB, fA, csO, snO, csE, snE, xvB, xvA, 0)
  }
  BODY(NS - 1, fA, fB, csE, snE, csO, snO, xvA, xvB, 1)

  // final exact normalize + store
  float nss = 0.f;
#pragma unroll
  for (int mt = 0; mt < 4; mt++)
#pragma unroll
    for (int r = 0; r < 4; r++) nss += u[mt][r] * u[mt][r];
  nss += __shfl_xor(nss, 16);
  nss += __shfl_xor(nss, 32);
  const float alpha = 1.f / (sqrtf(nss) + 1e-8f);

  float* eo = (dir ? envR : envL) + (size_t)b * 64;
#pragma unroll
  for (int mt = 0; mt < 4; mt++) {
    vf4 v;
#pragma unroll
    for (int r = 0; r < 4; r++) v[r] = u[mt][r] * alpha;
    *(vf4*)&eo[16 * mt + 4 * g] = v;
  }
}

// ---- center contraction (fp32) ----
__global__ __launch_bounds__(256) void centerk(const float* __restrict__ envL,
                                               const float* __restrict__ envR,
                                               const float* __restrict__ center,
                                               float* __restrict__ Pp) {
  __shared__ float Cs[2][SITE_F];
  __shared__ float LT[64 * 36];
  __shared__ float RT[64 * 36];
  const int bbase = blockIdx.x * 32;
  const int half = blockIdx.y;
  const int tid = threadIdx.x;
  const int och = tid & 31, bch = tid >> 5;
  const int o0 = och * 4, b0 = bch * 4;
#pragma unroll
  for (int m = 0; m < 8; m++) {
    const int idx = m * 256 + tid;
    const int b = idx >> 6, l = idx & 63;
    LT[l * 36 + b] = envL[(bbase + b) * 64 + l];
    RT[l * 36 + b] = envR[(bbase + b) * 64 + l];
  }
  stage32k_256(Cs[0], center + (half * 32) * SITE_F, tid);
  float acc[4][4] = {};
  for (int lh = 0; lh < 32; lh++) {
    __syncthreads();
    const int buf = lh & 1;
    if (lh + 1 < 32) stage32k_256(Cs[buf ^ 1], center + (half * 32 + lh + 1) * SITE_F, tid);
    const vf4 lv = *(const vf4*)&LT[(half * 32 + lh) * 36 + b0];
    const float* C = Cs[buf];
#pragma unroll
    for (int r = 0; r < 64; r++) {
      const vf4 rv = *(const vf4*)&RT[r * 36 + b0];
      const vf4 cv = *(const vf4*)&C[r * 128 + o0];
#pragma unroll
      for (int i2 = 0; i2 < 4; i2++) {
        const float w = lv[i2] * rv[i2];
        acc[i2][0] += w * cv[0];
        acc[i2][1] += w * cv[1];
        acc[i2][2] += w * cv[2];
        acc[i2][3] += w * cv[3];
      }
    }
  }
#pragma unroll
  for (int i2 = 0; i2 < 4; i2++) {
    vf4 v; v[0] = acc[i2][0]; v[1] = acc[i2][1]; v[2] = acc[i2][2]; v[3] = acc[i2][3];
    *(vf4*)&Pp[(size_t)half * BBATCH * 128 + (size_t)(bbase + b0 + i2) * 128 + o0] = v;
  }
}

// ---- combine halves + row-normalize ----
__global__ __launch_bounds__(256) void combinek(const float* __restrict__ P,
                                                float* __restrict__ out) {
  const float* P0 = P;
  const float* P1 = P + (size_t)BBATCH * 128;
  const int row = blockIdx.x * 8 + (threadIdx.x >> 5);
  const int o0 = (threadIdx.x & 31) * 4;
  vf4 v = *(const vf4*)&P0[(size_t)row * 128 + o0];
  const vf4 v1 = *(const vf4*)&P1[(size_t)row * 128 + o0];
  v += v1;
  float ss = v[0] * v[0] + v[1] * v[1] + v[2] * v[2] + v[3] * v[3];
#pragma unroll
  for (int m = 1; m < 32; m <<= 1) ss += __shfl_xor(ss, m);
  const float inv = 1.f / fmaxf(sqrtf(ss), 1e-12f);
  v *= inv;
  *(vf4*)&out[(size_t)row * 128 + o0] = v;
}

extern "C" void kernel_launch(void* const* d_in, const int* in_sizes, int n_in,
                              void* d_out, int out_size, void* d_ws, size_t ws_size,
                              hipStream_t stream) {
  const float* x = (const float*)d_in[0];
  const float* left0 = (const float*)d_in[1];
  const float* left_rest = (const float*)d_in[2];
  const float* center = (const float*)d_in[3];
  const float* right_rest = (const float*)d_in[4];
  const float* right_last = (const float*)d_in[5];
  float* out = (float*)d_out;

  char* wsb = (char*)d_ws;
  unsigned short* Wl = (unsigned short*)wsb;                       // 8.37 MB
  unsigned short* Wr = Wl + (size_t)NS * SITE_F;                   // 8.37 MB
  float* envL = (float*)(Wr + (size_t)NS * SITE_F);                // 1 MB
  float* envR = envL + (size_t)BBATCH * 64;                        // 1 MB
  float* Pp = envR + (size_t)BBATCH * 64;                          // 4.2 MB

  hipLaunchKernelGGL(prep, dim3(NS, 2), dim3(256), 0, stream,
                     left_rest, right_rest, Wl, Wr);
  hipLaunchKernelGGL(sweep, dim3(512), dim3(64), 0, stream,
                     x, left0, right_last, Wl, Wr, envL, envR);
  hipLaunchKernelGGL(centerk, dim3(BBATCH / 32, 2), dim3(256), 0, stream,
                     envL, envR, center, Pp);
  hipLaunchKernelGGL(combinek, dim3(BBATCH / 8), dim3(256), 0, stream, Pp, out);
}

// Round 8
// 381.807 us; speedup vs baseline: 1.9801x; 1.1313x over previous
//
#include <hip/hip_runtime.h>

typedef float vf4 __attribute__((ext_vector_type(4)));
typedef short short8 __attribute__((ext_vector_type(8)));
typedef unsigned short ushort8 __attribute__((ext_vector_type(8)));

#define LL 1024
#define DD 64
#define OO 128
#define BBATCH 4096
#define NS 511          // scan sites per sweep
#define SITE_F 8192     // elements per site tensor (64*2*64)

// ---- async global->LDS (used by centerk only) ----
__device__ __forceinline__ void gld_lds16(const float* g, float* l) {
  __builtin_amdgcn_global_load_lds(
      (const __attribute__((address_space(1))) unsigned int*)g,
      (__attribute__((address_space(3))) unsigned int*)l, 16, 0, 0);
}

__device__ __forceinline__ void stage32k_256(float* lds, const float* g, int tid) {
#pragma unroll
  for (int q = 0; q < 8; q++) {
    const int off = (q * 256 + tid) * 4;
    gld_lds16(g + off, lds + off);
  }
}

// ---- one-shot: build bf16 16x16x32-frag-major N = A - I for both sweeps ----
// layout: W[site][f][lane][j] bf16, f = mt*4+s (mt=M-tile 0..3, s=K-step 0..3)
// A elem: m = 16*mt + (lane&15); k = 32*s + 8*(lane>>4) + j  (k = 2*env_in + p)
// right buffer is site-reversed so the sweep always walks ascending.
__global__ __launch_bounds__(256) void prep(const float* __restrict__ lsrc,
                                            const float* __restrict__ rsrc,
                                            unsigned short* __restrict__ Wl,
                                            unsigned short* __restrict__ Wr) {
  __shared__ float S[SITE_F];
  const int site = blockIdx.x;
  const int dir = blockIdx.y;
  const int tid = threadIdx.x;
  const float* src = (dir ? rsrc : lsrc) + (size_t)site * SITE_F;
  unsigned short* dst = dir ? (Wr + (size_t)(NS - 1 - site) * SITE_F)
                            : (Wl + (size_t)site * SITE_F);
#pragma unroll
  for (int m = 0; m < 8; m++)
    *(vf4*)&S[(m * 256 + tid) * 4] = *(const vf4*)&src[(m * 256 + tid) * 4];
  __syncthreads();
#pragma unroll
  for (int q = 0; q < 4; q++) {
    const int slot = q * 256 + tid;           // 0..1023 = f*64 + lane
    const int lane = slot & 63, f = slot >> 6;
    const int mt = f >> 2, s = f & 3;
    const int g = lane >> 4, c = lane & 15;
    const int m = 16 * mt + c;
    ushort8 t;
#pragma unroll
    for (int j = 0; j < 8; j++) {
      const int k = 32 * s + 8 * g + j;
      float v;
      if (dir == 0) {
        const int l = k >> 1, p = k & 1;
        v = S[l * 128 + p * 64 + m] - ((m == l) ? 1.f : 0.f);
      } else {
        const int r = k >> 1, p = k & 1;
        v = S[m * 128 + p * 64 + r] - ((m == r) ? 1.f : 0.f);
      }
      const unsigned uu = __builtin_bit_cast(unsigned, v);
      t[j] = (unsigned short)((uu + 0x7FFFu + ((uu >> 16) & 1u)) >> 16);  // RNE
    }
    *(ushort8*)&dst[(size_t)slot * 8] = t;
  }
}

// ---- per-site body ----
// FC: frag buffer holding site I; reloaded in place with site I+2 (ring-2).
// CS/SN: cos/sin(site I); overwritten with site I+2's values.
// XV: holds x(I+2) entering; overwritten with x(I+4).
// sched_barrier(0) pins the reload so regalloc can't sink it (keeps the
// compiler's own counted vmcnt prefetch pipeline: AITER pattern, auto-emitted).
#define BODY(I, FC, CS, SN, XV, LAST)                                          \
  {                                                                            \
    short8 e2[4];                                                              \
    _Pragma("unroll")                                                          \
    for (int s = 0; s < 4; s++) {                                              \
      int pk[4];                                                               \
      _Pragma("unroll")                                                        \
      for (int t = 0; t < 4; t++) {                                            \
        const float f0 = u[s][t] * CS, f1 = u[s][t] * SN;                      \
        int p;                                                                 \
        asm("v_cvt_pk_bf16_f32 %0, %1, %2" : "=v"(p) : "v"(f0), "v"(f1));      \
        pk[t] = p;                                                             \
      }                                                                        \
      short8 e;                                                                \
      _Pragma("unroll")                                                        \
      for (int t = 0; t < 4; t++) {                                            \
        e[2 * t] = (short)(pk[t] & 0xFFFF);                                    \
        e[2 * t + 1] = (short)((unsigned)pk[t] >> 16);                         \
      }                                                                        \
      e2[s] = e;                                                               \
    }                                                                          \
    const float keff = CS + SN;                                                \
    vf4 acc[4];                                                                \
    _Pragma("unroll")                                                          \
    for (int mt = 0; mt < 4; mt++) {                                           \
      vf4 z;                                                                   \
      z[0] = keff * u[mt][0]; z[1] = keff * u[mt][1];                          \
      z[2] = keff * u[mt][2]; z[3] = keff * u[mt][3];                          \
      acc[mt] = z;                                                             \
    }                                                                          \
    _Pragma("unroll")                                                          \
    for (int mt = 0; mt < 4; mt++) {                                           \
      acc[mt] = __builtin_amdgcn_mfma_f32_16x16x32_bf16(                       \
          __builtin_bit_cast(short8, FC[mt * 4 + 0]), e2[0], acc[mt], 0, 0, 0);\
      acc[mt] = __builtin_amdgcn_mfma_f32_16x16x32_bf16(                       \
          __builtin_bit_cast(short8, FC[mt * 4 + 1]), e2[1], acc[mt], 0, 0, 0);\
      acc[mt] = __builtin_amdgcn_mfma_f32_16x16x32_bf16(                       \
          __builtin_bit_cast(short8, FC[mt * 4 + 2]), e2[2], acc[mt], 0, 0, 0);\
      acc[mt] = __builtin_amdgcn_mfma_f32_16x16x32_bf16(                       \
          __builtin_bit_cast(short8, FC[mt * 4 + 3]), e2[3], acc[mt], 0, 0, 0);\
    }                                                                          \
    if (!(LAST)) {                                                             \
      const float xcur = XV; /* x(I+2) */                                      \
      const unsigned short* Wn = W + (size_t)((I) + 2) * SITE_F;               \
      _Pragma("unroll")                                                        \
      for (int q = 0; q < 16; q++)                                             \
        FC[q] = *(const vf4*)&Wn[(q * 64 + lane) * 8];                         \
      XV = xrow[dir ? (1018 - (I)) : (5 + (I))]; /* x(I+4) */                  \
      __builtin_amdgcn_sched_barrier(0);                                       \
      const float qrev = 0.25f * xcur; /* cos(pi/2 x)=cos(2pi*(x/4)) */        \
      float c_, s_;                                                            \
      asm("v_cos_f32 %0, %1" : "=v"(c_) : "v"(qrev));                          \
      asm("v_sin_f32 %0, %1" : "=v"(s_) : "v"(qrev));                          \
      CS = c_;                                                                 \
      SN = s_;                                                                 \
    }                                                                          \
    _Pragma("unroll")                                                          \
    for (int mt = 0; mt < 4; mt++) u[mt] = acc[mt];                            \
    if (((I) & 7) == 7) { /* exact pow2 rescale, keeps fp32 in range */        \
      float nss = 0.f;                                                         \
      _Pragma("unroll")                                                        \
      for (int mt = 0; mt < 4; mt++)                                           \
        _Pragma("unroll")                                                      \
        for (int r = 0; r < 4; r++) nss += u[mt][r] * u[mt][r];                \
      nss += __shfl_xor(nss, 16);                                              \
      nss += __shfl_xor(nss, 32);                                              \
      const int eb = (__float_as_int(nss) >> 23) & 0xFF;                       \
      const float alpha = __int_as_float((127 - ((eb - 127) >> 1)) << 23);     \
      _Pragma("unroll")                                                        \
      for (int mt = 0; mt < 4; mt++)                                           \
        _Pragma("unroll")                                                      \
        for (int r = 0; r < 4; r++) u[mt][r] *= alpha;                         \
    }                                                                          \
  }

// ---- sweep: 1 wave = 16 chains; no LDS; pinned ring-2 register prefetch ----
// XCD swizzle: XCDs 0-3 -> dir 0, XCDs 4-7 -> dir 1; the 2 blocks/CU stream
// identical W addresses in near-lockstep -> L1/L2 reuse.
__global__ __launch_bounds__(64, 1) void sweep(const float* __restrict__ x,
                                               const float* __restrict__ left0,
                                               const float* __restrict__ right_last,
                                               const unsigned short* __restrict__ Wl,
                                               const unsigned short* __restrict__ Wr,
                                               float* __restrict__ envL,
                                               float* __restrict__ envR) {
  const int bid = blockIdx.x;
  const int xcd = bid & 7;
  const int inner = bid >> 3;            // 0..63
  const int dir = xcd >> 2;
  const int pr = (xcd & 3) * 64 + inner; // 0..255
  const int lane = threadIdx.x;
  const int g = lane >> 4, c = lane & 15;
  const int b = pr * 16 + c;
  const float* xrow = x + (size_t)b * LL;

  const unsigned short* W = dir ? Wr : Wl;

  // init env from boundary tensor (fp32, exact normalize)
  vf4 u[4];
  {
    const float x0 = xrow[dir ? (LL - 1) : 0];
    const float qrev = 0.25f * x0;
    float cs, sn;
    asm("v_cos_f32 %0, %1" : "=v"(cs) : "v"(qrev));
    asm("v_sin_f32 %0, %1" : "=v"(sn) : "v"(qrev));
#pragma unroll
    for (int mt = 0; mt < 4; mt++)
#pragma unroll
      for (int r = 0; r < 4; r++) {
        const int n = 16 * mt + 4 * g + r;
        const float w0 = dir ? right_last[n * 2] : left0[n];
        const float w1 = dir ? right_last[n * 2 + 1] : left0[64 + n];
        u[mt][r] = cs * w0 + sn * w1;
      }
    float ss = 0.f;
#pragma unroll
    for (int mt = 0; mt < 4; mt++)
#pragma unroll
      for (int r = 0; r < 4; r++) ss += u[mt][r] * u[mt][r];
    ss += __shfl_xor(ss, 16);
    ss += __shfl_xor(ss, 32);
    const float a0 = 1.f / (sqrtf(ss) + 1e-8f);
#pragma unroll
    for (int mt = 0; mt < 4; mt++)
#pragma unroll
      for (int r = 0; r < 4; r++) u[mt][r] *= a0;
  }

  // ---- prologue: frags(site0,site1) + cs/sn(0,1) + x ring (x(2),x(3)) ----
  vf4 fA[16], fB[16];
#pragma unroll
  for (int q = 0; q < 16; q++)
    fA[q] = *(const vf4*)&W[(q * 64 + lane) * 8];
#pragma unroll
  for (int q = 0; q < 16; q++)
    fB[q] = *(const vf4*)&W[(size_t)SITE_F + (q * 64 + lane) * 8];

  float csE, snE, csO, snO;
  {
    const float q0 = 0.25f * xrow[dir ? 1022 : 1];   // site 0
    asm("v_cos_f32 %0, %1" : "=v"(csE) : "v"(q0));
    asm("v_sin_f32 %0, %1" : "=v"(snE) : "v"(q0));
    const float q1 = 0.25f * xrow[dir ? 1021 : 2];   // site 1
    asm("v_cos_f32 %0, %1" : "=v"(csO) : "v"(q1));
    asm("v_sin_f32 %0, %1" : "=v"(snO) : "v"(q1));
  }
  float xvA = xrow[dir ? 1020 : 3];   // x(site 2)
  float xvB = xrow[dir ? 1019 : 4];   // x(site 3)

  // ---- main loop: sites 0..509 unrolled x2 (ring-2), tail site 510 ----
  for (int i = 0; i < NS - 1; i += 2) {
    BODY(i, fA, csE, snE, xvA, 0)
    BODY(i + 1, fB, csO, snO, xvB, 0)
  }
  BODY(NS - 1, fA, csE, snE, xvA, 1)

  // final exact normalize + store
  float nss = 0.f;
#pragma unroll
  for (int mt = 0; mt < 4; mt++)
#pragma unroll
    for (int r = 0; r < 4; r++) nss += u[mt][r] * u[mt][r];
  nss += __shfl_xor(nss, 16);
  nss += __shfl_xor(nss, 32);
  const float alpha = 1.f / (sqrtf(nss) + 1e-8f);

  float* eo = (dir ? envR : envL) + (size_t)b * 64;
#pragma unroll
  for (int mt = 0; mt < 4; mt++) {
    vf4 v;
#pragma unroll
    for (int r = 0; r < 4; r++) v[r] = u[mt][r] * alpha;
    *(vf4*)&eo[16 * mt + 4 * g] = v;
  }
}

// ---- center contraction (fp32) ----
__global__ __launch_bounds__(256) void centerk(const float* __restrict__ envL,
                                               const float* __restrict__ envR,
                                               const float* __restrict__ center,
                                               float* __restrict__ Pp) {
  __shared__ float Cs[2][SITE_F];
  __shared__ float LT[64 * 36];
  __shared__ float RT[64 * 36];
  const int bbase = blockIdx.x * 32;
  const int half = blockIdx.y;
  const int tid = threadIdx.x;
  const int och = tid & 31, bch = tid >> 5;
  const int o0 = och * 4, b0 = bch * 4;
#pragma unroll
  for (int m = 0; m < 8; m++) {
    const int idx = m * 256 + tid;
    const int b = idx >> 6, l = idx & 63;
    LT[l * 36 + b] = envL[(bbase + b) * 64 + l];
    RT[l * 36 + b] = envR[(bbase + b) * 64 + l];
  }
  stage32k_256(Cs[0], center + (half * 32) * SITE_F, tid);
  float acc[4][4] = {};
  for (int lh = 0; lh < 32; lh++) {
    __syncthreads();
    const int buf = lh & 1;
    if (lh + 1 < 32) stage32k_256(Cs[buf ^ 1], center + (half * 32 + lh + 1) * SITE_F, tid);
    const vf4 lv = *(const vf4*)&LT[(half * 32 + lh) * 36 + b0];
    const float* C = Cs[buf];
#pragma unroll
    for (int r = 0; r < 64; r++) {
      const vf4 rv = *(const vf4*)&RT[r * 36 + b0];
      const vf4 cv = *(const vf4*)&C[r * 128 + o0];
#pragma unroll
      for (int i2 = 0; i2 < 4; i2++) {
        const float w = lv[i2] * rv[i2];
        acc[i2][0] += w * cv[0];
        acc[i2][1] += w * cv[1];
        acc[i2][2] += w * cv[2];
        acc[i2][3] += w * cv[3];
      }
    }
  }
#pragma unroll
  for (int i2 = 0; i2 < 4; i2++) {
    vf4 v; v[0] = acc[i2][0]; v[1] = acc[i2][1]; v[2] = acc[i2][2]; v[3] = acc[i2][3];
    *(vf4*)&Pp[(size_t)half * BBATCH * 128 + (size_t)(bbase + b0 + i2) * 128 + o0] = v;
  }
}

// ---- combine halves + row-normalize ----
__global__ __launch_bounds__(256) void combinek(const float* __restrict__ P,
                                                float* __restrict__ out) {
  const float* P0 = P;
  const float* P1 = P + (size_t)BBATCH * 128;
  const int row = blockIdx.x * 8 + (threadIdx.x >> 5);
  const int o0 = (threadIdx.x & 31) * 4;
  vf4 v = *(const vf4*)&P0[(size_t)row * 128 + o0];
  const vf4 v1 = *(const vf4*)&P1[(size_t)row * 128 + o0];
  v += v1;
  float ss = v[0] * v[0] + v[1] * v[1] + v[2] * v[2] + v[3] * v[3];
#pragma unroll
  for (int m = 1; m < 32; m <<= 1) ss += __shfl_xor(ss, m);
  const float inv = 1.f / fmaxf(sqrtf(ss), 1e-12f);
  v *= inv;
  *(vf4*)&out[(size_t)row * 128 + o0] = v;
}

extern "C" void kernel_launch(void* const* d_in, const int* in_sizes, int n_in,
                              void* d_out, int out_size, void* d_ws, size_t ws_size,
                              hipStream_t stream) {
  const float* x = (const float*)d_in[0];
  const float* left0 = (const float*)d_in[1];
  const float* left_rest = (const float*)d_in[2];
  const float* center = (const float*)d_in[3];
  const float* right_rest = (const float*)d_in[4];
  const float* right_last = (const float*)d_in[5];
  float* out = (float*)d_out;

  char* wsb = (char*)d_ws;
  unsigned short* Wl = (unsigned short*)wsb;                       // 8.37 MB
  unsigned short* Wr = Wl + (size_t)NS * SITE_F;                   // 8.37 MB
  float* envL = (float*)(Wr + (size_t)NS * SITE_F);                // 1 MB
  float* envR = envL + (size_t)BBATCH * 64;                        // 1 MB
  float* Pp = envR + (size_t)BBATCH * 64;                          // 4.2 MB

  hipLaunchKernelGGL(prep, dim3(NS, 2), dim3(256), 0, stream,
                     left_rest, right_rest, Wl, Wr);
  hipLaunchKernelGGL(sweep, dim3(512), dim3(64), 0, stream,
                     x, left0, right_last, Wl, Wr, envL, envR);
  hipLaunchKernelGGL(centerk, dim3(BBATCH / 32, 2), dim3(256), 0, stream,
                     envL, envR, center, Pp);
  hipLaunchKernelGGL(combinek, dim3(BBATCH / 8), dim3(256), 0, stream, Pp, out);
}

// Round 9
// 376.092 us; speedup vs baseline: 2.0102x; 1.0152x over previous
//
#include <hip/hip_runtime.h>

typedef float vf4 __attribute__((ext_vector_type(4)));
typedef int vi4 __attribute__((ext_vector_type(4)));
typedef short short8 __attribute__((ext_vector_type(8)));
typedef unsigned short ushort8 __attribute__((ext_vector_type(8)));

#define LL 1024
#define DD 64
#define OO 128
#define BBATCH 4096
#define NS 511          // scan sites per sweep
#define SITE_F 8192     // elements per site tensor (64*2*64)

// ---- async global->LDS (used by centerk only) ----
__device__ __forceinline__ void gld_lds16(const float* g, float* l) {
  __builtin_amdgcn_global_load_lds(
      (const __attribute__((address_space(1))) unsigned int*)g,
      (__attribute__((address_space(3))) unsigned int*)l, 16, 0, 0);
}

__device__ __forceinline__ void stage32k_256(float* lds, const float* g, int tid) {
#pragma unroll
  for (int q = 0; q < 8; q++) {
    const int off = (q * 256 + tid) * 4;
    gld_lds16(g + off, lds + off);
  }
}

// ---- one-shot: build bf16 16x16x32-frag-major N = A - I for both sweeps ----
// layout: W[site][f][lane][j] bf16, f = mt*4+s (mt=M-tile 0..3, s=K-step 0..3)
// A elem: m = 16*mt + (lane&15); k = 32*s + 8*(lane>>4) + j  (k = 2*env_in + p)
// right buffer is site-reversed so the sweep always walks ascending.
__global__ __launch_bounds__(256) void prep(const float* __restrict__ lsrc,
                                            const float* __restrict__ rsrc,
                                            unsigned short* __restrict__ Wl,
                                            unsigned short* __restrict__ Wr) {
  __shared__ float S[SITE_F];
  const int site = blockIdx.x;
  const int dir = blockIdx.y;
  const int tid = threadIdx.x;
  const float* src = (dir ? rsrc : lsrc) + (size_t)site * SITE_F;
  unsigned short* dst = dir ? (Wr + (size_t)(NS - 1 - site) * SITE_F)
                            : (Wl + (size_t)site * SITE_F);
#pragma unroll
  for (int m = 0; m < 8; m++)
    *(vf4*)&S[(m * 256 + tid) * 4] = *(const vf4*)&src[(m * 256 + tid) * 4];
  __syncthreads();
#pragma unroll
  for (int q = 0; q < 4; q++) {
    const int slot = q * 256 + tid;           // 0..1023 = f*64 + lane
    const int lane = slot & 63, f = slot >> 6;
    const int mt = f >> 2, s = f & 3;
    const int g = lane >> 4, c = lane & 15;
    const int m = 16 * mt + c;
    ushort8 t;
#pragma unroll
    for (int j = 0; j < 8; j++) {
      const int k = 32 * s + 8 * g + j;
      float v;
      if (dir == 0) {
        const int l = k >> 1, p = k & 1;
        v = S[l * 128 + p * 64 + m] - ((m == l) ? 1.f : 0.f);
      } else {
        const int r = k >> 1, p = k & 1;
        v = S[m * 128 + p * 64 + r] - ((m == r) ? 1.f : 0.f);
      }
      const unsigned uu = __builtin_bit_cast(unsigned, v);
      t[j] = (unsigned short)((uu + 0x7FFFu + ((uu >> 16) & 1u)) >> 16);  // RNE
    }
    *(ushort8*)&dst[(size_t)slot * 8] = t;
  }
}

// ---- per-site body (ring-3) ----
// FC: frag buffer holding site I; reloaded in place with site I+3.
// CS/SN: cos/sin(site I); overwritten with site I+3's values.
// XS: holds x(I+3) entering; overwritten with x(I+6).
// sched_barrier(0) pins the reload block so it can't sink toward its use.
#define BODY(I, FC, CS, SN, XS, PF)                                            \
  {                                                                            \
    short8 e2[4];                                                              \
    _Pragma("unroll")                                                          \
    for (int s = 0; s < 4; s++) {                                              \
      int pk[4];                                                               \
      _Pragma("unroll")                                                        \
      for (int t = 0; t < 4; t++) {                                            \
        const float f0 = u[s][t] * CS, f1 = u[s][t] * SN;                      \
        int p;                                                                 \
        asm("v_cvt_pk_bf16_f32 %0, %1, %2" : "=v"(p) : "v"(f0), "v"(f1));      \
        pk[t] = p;                                                             \
      }                                                                        \
      e2[s] = __builtin_bit_cast(short8, (vi4){pk[0], pk[1], pk[2], pk[3]});   \
    }                                                                          \
    const float keff = CS + SN;                                                \
    vf4 acc[4];                                                                \
    _Pragma("unroll")                                                          \
    for (int mt = 0; mt < 4; mt++) {                                           \
      vf4 z;                                                                   \
      z[0] = keff * u[mt][0]; z[1] = keff * u[mt][1];                          \
      z[2] = keff * u[mt][2]; z[3] = keff * u[mt][3];                          \
      acc[mt] = z;                                                             \
    }                                                                          \
    _Pragma("unroll")                                                          \
    for (int mt = 0; mt < 4; mt++) {                                           \
      acc[mt] = __builtin_amdgcn_mfma_f32_16x16x32_bf16(                       \
          __builtin_bit_cast(short8, FC[mt * 4 + 0]), e2[0], acc[mt], 0, 0, 0);\
      acc[mt] = __builtin_amdgcn_mfma_f32_16x16x32_bf16(                       \
          __builtin_bit_cast(short8, FC[mt * 4 + 1]), e2[1], acc[mt], 0, 0, 0);\
      acc[mt] = __builtin_amdgcn_mfma_f32_16x16x32_bf16(                       \
          __builtin_bit_cast(short8, FC[mt * 4 + 2]), e2[2], acc[mt], 0, 0, 0);\
      acc[mt] = __builtin_amdgcn_mfma_f32_16x16x32_bf16(                       \
          __builtin_bit_cast(short8, FC[mt * 4 + 3]), e2[3], acc[mt], 0, 0, 0);\
    }                                                                          \
    if (PF) {                                                                  \
      const unsigned short* Wn = W + (size_t)((I) + 3) * SITE_F;               \
      _Pragma("unroll")                                                        \
      for (int q = 0; q < 16; q++)                                             \
        FC[q] = *(const vf4*)&Wn[(q * 64 + lane) * 8];                         \
      const float xt = XS; /* x(I+3) */                                        \
      const int nx = ((I) + 6 < NS) ? ((I) + 6) : (NS - 1);                    \
      XS = xrow[dir ? (1022 - nx) : (1 + nx)]; /* x(I+6) */                    \
      __builtin_amdgcn_sched_barrier(0);                                       \
      const float qrev = 0.25f * xt; /* cos(pi/2 x)=cos(2pi*(x/4)) */          \
      float c_, s_;                                                            \
      asm("v_cos_f32 %0, %1" : "=v"(c_) : "v"(qrev));                          \
      asm("v_sin_f32 %0, %1" : "=v"(s_) : "v"(qrev));                          \
      CS = c_;                                                                 \
      SN = s_;                                                                 \
    }                                                                          \
    _Pragma("unroll")                                                          \
    for (int mt = 0; mt < 4; mt++) u[mt] = acc[mt];                            \
    if (((I) & 7) == 7) { /* exact pow2 rescale, keeps fp32 in range */        \
      float nss = 0.f;                                                         \
      _Pragma("unroll")                                                        \
      for (int mt = 0; mt < 4; mt++)                                           \
        _Pragma("unroll")                                                      \
        for (int r = 0; r < 4; r++) nss += u[mt][r] * u[mt][r];                \
      nss += __shfl_xor(nss, 16);                                              \
      nss += __shfl_xor(nss, 32);                                              \
      const int eb = (__float_as_int(nss) >> 23) & 0xFF;                       \
      const float alpha = __int_as_float((127 - ((eb - 127) >> 1)) << 23);     \
      _Pragma("unroll")                                                        \
      for (int mt = 0; mt < 4; mt++)                                           \
        _Pragma("unroll")                                                      \
        for (int r = 0; r < 4; r++) u[mt][r] *= alpha;                         \
    }                                                                          \
  }

// ---- sweep: 1 wave = 16 chains; no LDS; ring-3 register prefetch ----
// XCD swizzle: XCDs 0-3 -> dir 0, XCDs 4-7 -> dir 1.
__global__ __launch_bounds__(64, 1) void sweep(const float* __restrict__ x,
                                               const float* __restrict__ left0,
                                               const float* __restrict__ right_last,
                                               const unsigned short* __restrict__ Wl,
                                               const unsigned short* __restrict__ Wr,
                                               float* __restrict__ envL,
                                               float* __restrict__ envR) {
  const int bid = blockIdx.x;
  const int xcd = bid & 7;
  const int inner = bid >> 3;            // 0..63
  const int dir = xcd >> 2;
  const int pr = (xcd & 3) * 64 + inner; // 0..255
  const int lane = threadIdx.x;
  const int g = lane >> 4, c = lane & 15;
  const int b = pr * 16 + c;
  const float* xrow = x + (size_t)b * LL;

  const unsigned short* W = dir ? Wr : Wl;

  // init env from boundary tensor (fp32, exact normalize)
  vf4 u[4];
  {
    const float x0 = xrow[dir ? (LL - 1) : 0];
    const float qrev = 0.25f * x0;
    float cs, sn;
    asm("v_cos_f32 %0, %1" : "=v"(cs) : "v"(qrev));
    asm("v_sin_f32 %0, %1" : "=v"(sn) : "v"(qrev));
#pragma unroll
    for (int mt = 0; mt < 4; mt++)
#pragma unroll
      for (int r = 0; r < 4; r++) {
        const int n = 16 * mt + 4 * g + r;
        const float w0 = dir ? right_last[n * 2] : left0[n];
        const float w1 = dir ? right_last[n * 2 + 1] : left0[64 + n];
        u[mt][r] = cs * w0 + sn * w1;
      }
    float ss = 0.f;
#pragma unroll
    for (int mt = 0; mt < 4; mt++)
#pragma unroll
      for (int r = 0; r < 4; r++) ss += u[mt][r] * u[mt][r];
    ss += __shfl_xor(ss, 16);
    ss += __shfl_xor(ss, 32);
    const float a0 = 1.f / (sqrtf(ss) + 1e-8f);
#pragma unroll
    for (int mt = 0; mt < 4; mt++)
#pragma unroll
      for (int r = 0; r < 4; r++) u[mt][r] *= a0;
  }

  // ---- prologue: frags(sites 0..2), cs/sn(0..2), x ring = x(3..5) ----
  vf4 fA[16], fB[16], fC[16];
#pragma unroll
  for (int q = 0; q < 16; q++)
    fA[q] = *(const vf4*)&W[(q * 64 + lane) * 8];
#pragma unroll
  for (int q = 0; q < 16; q++)
    fB[q] = *(const vf4*)&W[(size_t)SITE_F + (q * 64 + lane) * 8];
#pragma unroll
  for (int q = 0; q < 16; q++)
    fC[q] = *(const vf4*)&W[(size_t)2 * SITE_F + (q * 64 + lane) * 8];

  float cs0, sn0, cs1, sn1, cs2, sn2;
  {
    const float q0 = 0.25f * xrow[dir ? 1022 : 1];   // site 0
    asm("v_cos_f32 %0, %1" : "=v"(cs0) : "v"(q0));
    asm("v_sin_f32 %0, %1" : "=v"(sn0) : "v"(q0));
    const float q1 = 0.25f * xrow[dir ? 1021 : 2];   // site 1
    asm("v_cos_f32 %0, %1" : "=v"(cs1) : "v"(q1));
    asm("v_sin_f32 %0, %1" : "=v"(sn1) : "v"(q1));
    const float q2 = 0.25f * xrow[dir ? 1020 : 3];   // site 2
    asm("v_cos_f32 %0, %1" : "=v"(cs2) : "v"(q2));
    asm("v_sin_f32 %0, %1" : "=v"(sn2) : "v"(q2));
  }
  float x0v = xrow[dir ? 1019 : 4];   // x(site 3)
  float x1v = xrow[dir ? 1018 : 5];   // x(site 4)
  float x2v = xrow[dir ? 1017 : 6];   // x(site 5)

  // ---- main loop: sites 0..506 in steps of 3 (ring-3), tail 507..510 ----
  for (int i = 0; i < 505; i += 3) {
    BODY(i, fA, cs0, sn0, x0v, 1)
    BODY(i + 1, fB, cs1, sn1, x1v, 1)
    BODY(i + 2, fC, cs2, sn2, x2v, 1)
  }
  BODY(507, fA, cs0, sn0, x0v, 1)   // prefetches site 510 into fA
  BODY(508, fB, cs1, sn1, x1v, 0)
  BODY(509, fC, cs2, sn2, x2v, 0)
  BODY(510, fA, cs0, sn0, x0v, 0)

  // final exact normalize + store
  float nss = 0.f;
#pragma unroll
  for (int mt = 0; mt < 4; mt++)
#pragma unroll
    for (int r = 0; r < 4; r++) nss += u[mt][r] * u[mt][r];
  nss += __shfl_xor(nss, 16);
  nss += __shfl_xor(nss, 32);
  const float alpha = 1.f / (sqrtf(nss) + 1e-8f);

  float* eo = (dir ? envR : envL) + (size_t)b * 64;
#pragma unroll
  for (int mt = 0; mt < 4; mt++) {
    vf4 v;
#pragma unroll
    for (int r = 0; r < 4; r++) v[r] = u[mt][r] * alpha;
    *(vf4*)&eo[16 * mt + 4 * g] = v;
  }
}

// ---- center contraction (fp32) ----
__global__ __launch_bounds__(256) void centerk(const float* __restrict__ envL,
                                               const float* __restrict__ envR,
                                               const float* __restrict__ center,
                                               float* __restrict__ Pp) {
  __shared__ float Cs[2][SITE_F];
  __shared__ float LT[64 * 36];
  __shared__ float RT[64 * 36];
  const int bbase = blockIdx.x * 32;
  const int half = blockIdx.y;
  const int tid = threadIdx.x;
  const int och = tid & 31, bch = tid >> 5;
  const int o0 = och * 4, b0 = bch * 4;
#pragma unroll
  for (int m = 0; m < 8; m++) {
    const int idx = m * 256 + tid;
    const int b = idx >> 6, l = idx & 63;
    LT[l * 36 + b] = envL[(bbase + b) * 64 + l];
    RT[l * 36 + b] = envR[(bbase + b) * 64 + l];
  }
  stage32k_256(Cs[0], center + (half * 32) * SITE_F, tid);
  float acc[4][4] = {};
  for (int lh = 0; lh < 32; lh++) {
    __syncthreads();
    const int buf = lh & 1;
    if (lh + 1 < 32) stage32k_256(Cs[buf ^ 1], center + (half * 32 + lh + 1) * SITE_F, tid);
    const vf4 lv = *(const vf4*)&LT[(half * 32 + lh) * 36 + b0];
    const float* C = Cs[buf];
#pragma unroll
    for (int r = 0; r < 64; r++) {
      const vf4 rv = *(const vf4*)&RT[r * 36 + b0];
      const vf4 cv = *(const vf4*)&C[r * 128 + o0];
#pragma unroll
      for (int i2 = 0; i2 < 4; i2++) {
        const float w = lv[i2] * rv[i2];
        acc[i2][0] += w * cv[0];
        acc[i2][1] += w * cv[1];
        acc[i2][2] += w * cv[2];
        acc[i2][3] += w * cv[3];
      }
    }
  }
#pragma unroll
  for (int i2 = 0; i2 < 4; i2++) {
    vf4 v; v[0] = acc[i2][0]; v[1] = acc[i2][1]; v[2] = acc[i2][2]; v[3] = acc[i2][3];
    *(vf4*)&Pp[(size_t)half * BBATCH * 128 + (size_t)(bbase + b0 + i2) * 128 + o0] = v;
  }
}

// ---- combine halves + row-normalize ----
__global__ __launch_bounds__(256) void combinek(const float* __restrict__ P,
                                                float* __restrict__ out) {
  const float* P0 = P;
  const float* P1 = P + (size_t)BBATCH * 128;
  const int row = blockIdx.x * 8 + (threadIdx.x >> 5);
  const int o0 = (threadIdx.x & 31) * 4;
  vf4 v = *(const vf4*)&P0[(size_t)row * 128 + o0];
  const vf4 v1 = *(const vf4*)&P1[(size_t)row * 128 + o0];
  v += v1;
  float ss = v[0] * v[0] + v[1] * v[1] + v[2] * v[2] + v[3] * v[3];
#pragma unroll
  for (int m = 1; m < 32; m <<= 1) ss += __shfl_xor(ss, m);
  const float inv = 1.f / fmaxf(sqrtf(ss), 1e-12f);
  v *= inv;
  *(vf4*)&out[(size_t)row * 128 + o0] = v;
}

extern "C" void kernel_launch(void* const* d_in, const int* in_sizes, int n_in,
                              void* d_out, int out_size, void* d_ws, size_t ws_size,
                              hipStream_t stream) {
  const float* x = (const float*)d_in[0];
  const float* left0 = (const float*)d_in[1];
  const float* left_rest = (const float*)d_in[2];
  const float* center = (const float*)d_in[3];
  const float* right_rest = (const float*)d_in[4];
  const float* right_last = (const float*)d_in[5];
  float* out = (float*)d_out;

  char* wsb = (char*)d_ws;
  unsigned short* Wl = (unsigned short*)wsb;                       // 8.37 MB
  unsigned short* Wr = Wl + (size_t)NS * SITE_F;                   // 8.37 MB
  float* envL = (float*)(Wr + (size_t)NS * SITE_F);                // 1 MB
  float* envR = envL + (size_t)BBATCH * 64;                        // 1 MB
  float* Pp = envR + (size_t)BBATCH * 64;                          // 4.2 MB

  hipLaunchKernelGGL(prep, dim3(NS, 2), dim3(256), 0, stream,
                     left_rest, right_rest, Wl, Wr);
  hipLaunchKernelGGL(sweep, dim3(512), dim3(64), 0, stream,
                     x, left0, right_last, Wl, Wr, envL, envR);
  hipLaunchKernelGGL(centerk, dim3(BBATCH / 32, 2), dim3(256), 0, stream,
                     envL, envR, center, Pp);
  hipLaunchKernelGGL(combinek, dim3(BBATCH / 8), dim3(256), 0, stream, Pp, out);
}